// Round 2
// baseline (326.957 us; speedup 1.0000x reference)
//
#include <hip/hip_runtime.h>
#include <stdint.h>

#define SEQ 2048
#define DM 1024
#define NHEAD 16
#define HD 64

typedef __attribute__((ext_vector_type(8))) __bf16 bf16x8;
typedef __attribute__((ext_vector_type(4))) __bf16 bf16x4;
typedef __attribute__((ext_vector_type(4))) float f32x4;
typedef __attribute__((ext_vector_type(4))) short s16x4;
typedef __attribute__((ext_vector_type(4))) unsigned short u16x4;
typedef __attribute__((ext_vector_type(8))) unsigned short u16x8;
typedef __attribute__((ext_vector_type(4))) unsigned int u32x4;

// round-to-nearest-even f32 -> bf16 bits
__device__ __forceinline__ unsigned short f2b(float f) {
  unsigned u = __builtin_bit_cast(unsigned, f);
  return (unsigned short)((u + 0x7FFFu + ((u >> 16) & 1u)) >> 16);
}

__device__ __forceinline__ void gload16(const void* g, void* l) {
  __builtin_amdgcn_global_load_lds((__attribute__((address_space(1))) void*)g,
                                   (__attribute__((address_space(3))) void*)l,
                                   16, 0, 0);
}

// ---------------- conversion kernels ----------------

__global__ __launch_bounds__(256) void k_conv_x(const float* __restrict__ x,
                                                unsigned short* __restrict__ xb) {
  size_t i = (size_t)blockIdx.x * 256 + threadIdx.x;  // 8 elems per thread
  const f32x4* xv = (const f32x4*)x;
  f32x4 a = xv[i * 2], b = xv[i * 2 + 1];
  u16x8 o;
  o[0] = f2b(a[0]); o[1] = f2b(a[1]); o[2] = f2b(a[2]); o[3] = f2b(a[3]);
  o[4] = f2b(b[0]); o[5] = f2b(b[1]); o[6] = f2b(b[2]); o[7] = f2b(b[3]);
  ((u16x8*)xb)[i] = o;
}

// transpose + convert: out[z][n][k] = W_z[k][n]  (bf16)
__global__ __launch_bounds__(256) void k_conv_wt(const float* __restrict__ W0,
                                                 const float* __restrict__ W1,
                                                 const float* __restrict__ W2,
                                                 const float* __restrict__ W3,
                                                 unsigned short* __restrict__ out) {
  __shared__ float t[32][33];
  int z = blockIdx.z;
  const float* W = (z == 0) ? W0 : (z == 1) ? W1 : (z == 2) ? W2 : W3;
  unsigned short* o = out + (size_t)z * DM * DM;
  int tid = threadIdx.x;
  int r = tid >> 3, c4 = (tid & 7) << 2;
  f32x4 v = *(const f32x4*)&W[(size_t)(blockIdx.y * 32 + r) * DM + blockIdx.x * 32 + c4];
  t[r][c4 + 0] = v[0]; t[r][c4 + 1] = v[1]; t[r][c4 + 2] = v[2]; t[r][c4 + 3] = v[3];
  __syncthreads();
  u16x4 ov;
  ov[0] = f2b(t[c4 + 0][r]); ov[1] = f2b(t[c4 + 1][r]);
  ov[2] = f2b(t[c4 + 2][r]); ov[3] = f2b(t[c4 + 3][r]);
  *(u16x4*)&o[(size_t)(blockIdx.x * 32 + r) * DM + blockIdx.y * 32 + c4] = ov;
}

// classify mask dtype: flag=0 -> byte mask (bool/u8); flag=1 -> 32-bit words (i32 or f32), test word != 0
__global__ void k_probe(const unsigned* __restrict__ m, unsigned* __restrict__ flag) {
  int t = threadIdx.x;
  bool small_all = true, f32seen = false;
  #pragma unroll
  for (int e = 0; e < 4; ++e) {
    unsigned w = m[t * 4 + e];
    if (w > 1u) small_all = false;
    if (w == 0x3f800000u) f32seen = true;
  }
  unsigned long long ba = __ballot(small_all);
  unsigned long long bf = __ballot(f32seen);
  if (t == 0) *flag = bf ? 1u : (ba == ~0ull ? 1u : 0u);
}

// ---------------- GEMM kernels (m97-style 128x128, BK=32) ----------------

#define BM 128
#define BN 128
#define BK 32

// C = A[4096x1024] * Wt_z^T ; z=0 -> Q (scaled 1/8, bf16 row-major), z=1 -> K, z=2 -> V transposed [B*H*64][SEQ]
__global__ __launch_bounds__(256) void k_gemm_qkv(const unsigned short* __restrict__ A,
                                                  const unsigned short* __restrict__ Wt,
                                                  unsigned short* __restrict__ Qb,
                                                  unsigned short* __restrict__ Kb,
                                                  unsigned short* __restrict__ Vt) {
  __shared__ unsigned short As[BM * BK];
  __shared__ unsigned short Bs[BN * BK];
  int z = blockIdx.y;
  const unsigned short* Bt = Wt + (size_t)z * DM * DM;
  int tid = threadIdx.x;
  int lane = tid & 63, w = tid >> 6;
  int li = lane & 15, g = lane >> 4;
  int bm = blockIdx.x >> 3, bn = blockIdx.x & 7;
  int row0 = bm * BM, col0 = bn * BN;
  int m0 = (w >> 1) * 64, n0 = (w & 1) * 64;
  f32x4 acc[4][4];
  #pragma unroll
  for (int i = 0; i < 4; ++i)
    #pragma unroll
    for (int j = 0; j < 4; ++j) acc[i][j] = (f32x4){0.f, 0.f, 0.f, 0.f};

  const unsigned short* Ag = A + (size_t)(row0 + (tid >> 2)) * DM + (tid & 3) * 8;
  const unsigned short* Bg = Bt + (size_t)(col0 + (tid >> 2)) * DM + (tid & 3) * 8;
  unsigned short* Asl = As + tid * 8;
  unsigned short* Bsl = Bs + tid * 8;

  for (int kk = 0; kk < DM; kk += BK) {
    gload16(Ag + kk, Asl);
    gload16(Ag + kk + (size_t)64 * DM, Asl + 2048);
    gload16(Bg + kk, Bsl);
    gload16(Bg + kk + (size_t)64 * DM, Bsl + 2048);
    __syncthreads();
    bf16x8 af[4], bfr[4];
    #pragma unroll
    for (int mi = 0; mi < 4; ++mi)
      af[mi] = *(const bf16x8*)(As + (m0 + mi * 16 + li) * BK + g * 8);
    #pragma unroll
    for (int ni = 0; ni < 4; ++ni)
      bfr[ni] = *(const bf16x8*)(Bs + (n0 + ni * 16 + li) * BK + g * 8);
    #pragma unroll
    for (int mi = 0; mi < 4; ++mi)
      #pragma unroll
      for (int ni = 0; ni < 4; ++ni)
        acc[mi][ni] = __builtin_amdgcn_mfma_f32_16x16x32_bf16(af[mi], bfr[ni], acc[mi][ni], 0, 0, 0);
    __syncthreads();
  }

  if (z == 2) {
    // V transposed: Vt[(b*1024 + n)][s], 4 consecutive s per lane -> 8B stores
    #pragma unroll
    for (int mi = 0; mi < 4; ++mi)
      #pragma unroll
      for (int ni = 0; ni < 4; ++ni) {
        int mb = row0 + m0 + mi * 16 + g * 4;
        int n = col0 + n0 + ni * 16 + li;
        int bb = mb >> 11, s = mb & 2047;
        u16x4 ov;
        #pragma unroll
        for (int r = 0; r < 4; ++r) ov[r] = f2b(acc[mi][ni][r]);
        *(u16x4*)&Vt[((size_t)(bb * DM + n)) * SEQ + s] = ov;
      }
  } else {
    unsigned short* O = (z == 0) ? Qb : Kb;
    float sc = (z == 0) ? 0.125f : 1.0f;
    #pragma unroll
    for (int mi = 0; mi < 4; ++mi)
      #pragma unroll
      for (int ni = 0; ni < 4; ++ni) {
        int n = col0 + n0 + ni * 16 + li;
        #pragma unroll
        for (int r = 0; r < 4; ++r) {
          int m = row0 + m0 + mi * 16 + g * 4 + r;
          O[(size_t)m * DM + n] = f2b(acc[mi][ni][r] * sc);
        }
      }
  }
}

__global__ __launch_bounds__(256) void k_gemm_o(const unsigned short* __restrict__ A,
                                                const unsigned short* __restrict__ Bt,
                                                const float* __restrict__ bo,
                                                float* __restrict__ out) {
  __shared__ unsigned short As[BM * BK];
  __shared__ unsigned short Bs[BN * BK];
  int tid = threadIdx.x;
  int lane = tid & 63, w = tid >> 6;
  int li = lane & 15, g = lane >> 4;
  int bm = blockIdx.x >> 3, bn = blockIdx.x & 7;
  int row0 = bm * BM, col0 = bn * BN;
  int m0 = (w >> 1) * 64, n0 = (w & 1) * 64;
  f32x4 acc[4][4];
  #pragma unroll
  for (int i = 0; i < 4; ++i)
    #pragma unroll
    for (int j = 0; j < 4; ++j) acc[i][j] = (f32x4){0.f, 0.f, 0.f, 0.f};

  const unsigned short* Ag = A + (size_t)(row0 + (tid >> 2)) * DM + (tid & 3) * 8;
  const unsigned short* Bg = Bt + (size_t)(col0 + (tid >> 2)) * DM + (tid & 3) * 8;
  unsigned short* Asl = As + tid * 8;
  unsigned short* Bsl = Bs + tid * 8;

  for (int kk = 0; kk < DM; kk += BK) {
    gload16(Ag + kk, Asl);
    gload16(Ag + kk + (size_t)64 * DM, Asl + 2048);
    gload16(Bg + kk, Bsl);
    gload16(Bg + kk + (size_t)64 * DM, Bsl + 2048);
    __syncthreads();
    bf16x8 af[4], bfr[4];
    #pragma unroll
    for (int mi = 0; mi < 4; ++mi)
      af[mi] = *(const bf16x8*)(As + (m0 + mi * 16 + li) * BK + g * 8);
    #pragma unroll
    for (int ni = 0; ni < 4; ++ni)
      bfr[ni] = *(const bf16x8*)(Bs + (n0 + ni * 16 + li) * BK + g * 8);
    #pragma unroll
    for (int mi = 0; mi < 4; ++mi)
      #pragma unroll
      for (int ni = 0; ni < 4; ++ni)
        acc[mi][ni] = __builtin_amdgcn_mfma_f32_16x16x32_bf16(af[mi], bfr[ni], acc[mi][ni], 0, 0, 0);
    __syncthreads();
  }

  #pragma unroll
  for (int mi = 0; mi < 4; ++mi)
    #pragma unroll
    for (int ni = 0; ni < 4; ++ni) {
      int n = col0 + n0 + ni * 16 + li;
      float bias = bo[n];
      #pragma unroll
      for (int r = 0; r < 4; ++r) {
        int m = row0 + m0 + mi * 16 + g * 4 + r;
        out[(size_t)m * DM + n] = acc[mi][ni][r] + bias;
      }
    }
}

// ---------------- flash attention, 1 wave per 32 q-rows ----------------
// Q pre-scaled by 1/8. Sᵀ = K·Qᵀ via mfma_16x16x32 (C-frag: col=lane&15 = query, row=(lane>>4)*4+r = key).
// PV: outᵀ = Vᵀ·Pᵀ via mfma_16x16x16; the Sᵀ C-frag IS the Pᵀ B-fragment (zero shuffles).
__global__ __launch_bounds__(64) void k_attn(const unsigned short* __restrict__ Qm,
                                             const unsigned short* __restrict__ Km,
                                             const unsigned short* __restrict__ Vt,
                                             const void* __restrict__ maskp,
                                             const unsigned* __restrict__ flagp,
                                             unsigned short* __restrict__ AO) {
  const int lane = threadIdx.x;
  const int li = lane & 15, g = lane >> 4;
  const int q0 = blockIdx.x * 32;
  const int h = blockIdx.y;
  const int b = blockIdx.z;
  const unsigned mflag = *flagp;
  const size_t qrow0 = (size_t)b * SEQ + q0;

  bf16x8 qf[2][2];
  #pragma unroll
  for (int is = 0; is < 2; ++is)
    #pragma unroll
    for (int kc = 0; kc < 2; ++kc)
      qf[is][kc] = *(const bf16x8*)(Qm + (qrow0 + is * 16 + li) * DM + h * HD + kc * 32 + g * 8);

  f32x4 acc[2][4];
  #pragma unroll
  for (int is = 0; is < 2; ++is)
    #pragma unroll
    for (int ds = 0; ds < 4; ++ds) acc[is][ds] = (f32x4){0.f, 0.f, 0.f, 0.f};
  float mrow[2] = {-1e30f, -1e30f};
  float lrow[2] = {0.f, 0.f};

  const unsigned short* Kbase = Km + (size_t)b * SEQ * DM + h * HD + g * 8;
  const unsigned short* Vbase = Vt + (size_t)(b * NHEAD + h) * HD * SEQ + g * 4;
  const uint8_t* mask8 = (const uint8_t*)maskp + (size_t)b * SEQ * SEQ;
  const unsigned* mask32 = (const unsigned*)maskp + (size_t)b * SEQ * SEQ;

  for (int j0 = 0; j0 < SEQ; j0 += 16) {
    bf16x8 kf0 = *(const bf16x8*)(Kbase + (size_t)(j0 + li) * DM);
    bf16x8 kf1 = *(const bf16x8*)(Kbase + (size_t)(j0 + li) * DM + 32);
    s16x4 vf[4];
    #pragma unroll
    for (int ds = 0; ds < 4; ++ds)
      vf[ds] = *(const s16x4*)(Vbase + (size_t)(ds * 16 + li) * SEQ + j0);

    #pragma unroll
    for (int is = 0; is < 2; ++is) {
      f32x4 zz = (f32x4){0.f, 0.f, 0.f, 0.f};
      f32x4 st = __builtin_amdgcn_mfma_f32_16x16x32_bf16(kf0, qf[is][0], zz, 0, 0, 0);
      st = __builtin_amdgcn_mfma_f32_16x16x32_bf16(kf1, qf[is][1], st, 0, 0, 0);
      const int irow = q0 + is * 16 + li;
      unsigned kp[4];
      if (mflag == 0) {
        unsigned wm = *(const unsigned*)(mask8 + (size_t)irow * SEQ + j0 + g * 4);
        kp[0] = wm & 0xffu; kp[1] = wm & 0xff00u; kp[2] = wm & 0xff0000u; kp[3] = wm & 0xff000000u;
      } else {
        u32x4 wv = *(const u32x4*)(mask32 + (size_t)irow * SEQ + j0 + g * 4);
        kp[0] = wv[0]; kp[1] = wv[1]; kp[2] = wv[2]; kp[3] = wv[3];
      }
      float sv[4];
      float tm = -1e30f;
      #pragma unroll
      for (int r = 0; r < 4; ++r) {
        sv[r] = st[r];
        tm = fmaxf(tm, kp[r] ? sv[r] : -1e30f);
      }
      tm = fmaxf(tm, __shfl_xor(tm, 16));
      tm = fmaxf(tm, __shfl_xor(tm, 32));
      float mnew = fmaxf(mrow[is], tm);
      float alpha = __expf(mrow[is] - mnew);
      mrow[is] = mnew;
      float ps = 0.f;
      bf16x4 pb;
      #pragma unroll
      for (int r = 0; r < 4; ++r) {
        float p = kp[r] ? __expf(sv[r] - mnew) : 0.f;
        ps += p;
        pb[r] = (__bf16)p;
      }
      ps += __shfl_xor(ps, 16);
      ps += __shfl_xor(ps, 32);
      lrow[is] = lrow[is] * alpha + ps;
      s16x4 pf = __builtin_bit_cast(s16x4, pb);
      #pragma unroll
      for (int ds = 0; ds < 4; ++ds) {
        acc[is][ds] *= alpha;
        acc[is][ds] = __builtin_amdgcn_mfma_f32_16x16x16bf16_1k(vf[ds], pf, acc[is][ds], 0, 0, 0);
      }
    }
  }

  #pragma unroll
  for (int is = 0; is < 2; ++is) {
    float inv = 1.f / fmaxf(lrow[is], 1e-9f);
    #pragma unroll
    for (int ds = 0; ds < 4; ++ds) {
      u16x4 ov;
      #pragma unroll
      for (int r = 0; r < 4; ++r) ov[r] = f2b(acc[is][ds][r] * inv);
      *(u16x4*)(AO + (qrow0 + is * 16 + li) * DM + h * HD + ds * 16 + g * 4) = ov;
    }
  }
}

// ---------------- launch ----------------

extern "C" void kernel_launch(void* const* d_in, const int* in_sizes, int n_in,
                              void* d_out, int out_size, void* d_ws, size_t ws_size,
                              hipStream_t stream) {
  const float* x = (const float*)d_in[0];
  const void* mk = d_in[1];
  const float* Wq = (const float*)d_in[2];
  const float* Wk = (const float*)d_in[3];
  const float* Wv = (const float*)d_in[4];
  const float* Wo = (const float*)d_in[5];
  const float* bo = (const float*)d_in[6];
  float* out = (float*)d_out;
  char* ws = (char*)d_ws;

  // workspace layout (40 MB + 4 B):
  //   [0,8)   MB : xb  (bf16 x)  -- dead after k_gemm_qkv; reused as AO
  //   [8,16)  MB : wt  (4x Wt^T bf16)
  //   [16,24) MB : Qb
  //   [24,32) MB : Kb
  //   [32,40) MB : Vt
  //   40 MB      : flag
  unsigned short* xb = (unsigned short*)(ws);
  unsigned short* wt = (unsigned short*)(ws + ((size_t)8 << 20));
  unsigned short* Qb = (unsigned short*)(ws + ((size_t)16 << 20));
  unsigned short* Kb = (unsigned short*)(ws + ((size_t)24 << 20));
  unsigned short* Vt = (unsigned short*)(ws + ((size_t)32 << 20));
  unsigned short* AO = xb;  // alias: xb dead after k_gemm_qkv
  unsigned* flag = (unsigned*)(ws + ((size_t)40 << 20));

  hipLaunchKernelGGL(k_conv_x, dim3(2048), dim3(256), 0, stream, x, xb);
  hipLaunchKernelGGL(k_conv_wt, dim3(32, 32, 4), dim3(256), 0, stream, Wq, Wk, Wv, Wo, wt);
  hipLaunchKernelGGL(k_probe, dim3(1), dim3(64), 0, stream, (const unsigned*)mk, flag);
  hipLaunchKernelGGL(k_gemm_qkv, dim3(256, 3), dim3(256), 0, stream, xb, wt, Qb, Kb, Vt);
  hipLaunchKernelGGL(k_attn, dim3(SEQ / 32, NHEAD, 2), dim3(64), 0, stream, Qb, Kb, Vt, mk, flag, AO);
  hipLaunchKernelGGL(k_gemm_o, dim3(256), dim3(256), 0, stream, AO, wt + (size_t)3 * DM * DM, bo, out);
}

// Round 3
// 288.569 us; speedup vs baseline: 1.1330x; 1.1330x over previous
//
#include <hip/hip_runtime.h>
#include <stdint.h>

#define SEQ 2048
#define DM 1024
#define NHEAD 16
#define HD 64

typedef __attribute__((ext_vector_type(8))) __bf16 bf16x8;
typedef __attribute__((ext_vector_type(4))) __bf16 bf16x4;
typedef __attribute__((ext_vector_type(4))) float f32x4;
typedef __attribute__((ext_vector_type(4))) short s16x4;
typedef __attribute__((ext_vector_type(4))) unsigned short u16x4;
typedef __attribute__((ext_vector_type(8))) unsigned short u16x8;
typedef __attribute__((ext_vector_type(4))) unsigned int u32x4;

// round-to-nearest-even f32 -> bf16 bits
__device__ __forceinline__ unsigned short f2b(float f) {
  unsigned u = __builtin_bit_cast(unsigned, f);
  return (unsigned short)((u + 0x7FFFu + ((u >> 16) & 1u)) >> 16);
}

__device__ __forceinline__ void gload16(const void* g, void* l) {
  __builtin_amdgcn_global_load_lds((__attribute__((address_space(1))) void*)g,
                                   (__attribute__((address_space(3))) void*)l,
                                   16, 0, 0);
}

// ---------------- conversion kernels ----------------

__global__ __launch_bounds__(256) void k_conv_x(const float* __restrict__ x,
                                                unsigned short* __restrict__ xb) {
  size_t i = (size_t)blockIdx.x * 256 + threadIdx.x;  // 8 elems per thread
  const f32x4* xv = (const f32x4*)x;
  f32x4 a = xv[i * 2], b = xv[i * 2 + 1];
  u16x8 o;
  o[0] = f2b(a[0]); o[1] = f2b(a[1]); o[2] = f2b(a[2]); o[3] = f2b(a[3]);
  o[4] = f2b(b[0]); o[5] = f2b(b[1]); o[6] = f2b(b[2]); o[7] = f2b(b[3]);
  ((u16x8*)xb)[i] = o;
}

// transpose + convert: out[z][n][k] = W_z[k][n]  (bf16)
__global__ __launch_bounds__(256) void k_conv_wt(const float* __restrict__ W0,
                                                 const float* __restrict__ W1,
                                                 const float* __restrict__ W2,
                                                 const float* __restrict__ W3,
                                                 unsigned short* __restrict__ out) {
  __shared__ float t[32][33];
  int z = blockIdx.z;
  const float* W = (z == 0) ? W0 : (z == 1) ? W1 : (z == 2) ? W2 : W3;
  unsigned short* o = out + (size_t)z * DM * DM;
  int tid = threadIdx.x;
  int r = tid >> 3, c4 = (tid & 7) << 2;
  f32x4 v = *(const f32x4*)&W[(size_t)(blockIdx.y * 32 + r) * DM + blockIdx.x * 32 + c4];
  t[r][c4 + 0] = v[0]; t[r][c4 + 1] = v[1]; t[r][c4 + 2] = v[2]; t[r][c4 + 3] = v[3];
  __syncthreads();
  u16x4 ov;
  ov[0] = f2b(t[c4 + 0][r]); ov[1] = f2b(t[c4 + 1][r]);
  ov[2] = f2b(t[c4 + 2][r]); ov[3] = f2b(t[c4 + 3][r]);
  *(u16x4*)&o[(size_t)(blockIdx.x * 32 + r) * DM + blockIdx.y * 32 + c4] = ov;
}

// classify mask dtype: flag=0 -> byte mask (bool/u8); flag=1 -> 32-bit words (i32 or f32), test word != 0
__global__ void k_probe(const unsigned* __restrict__ m, unsigned* __restrict__ flag) {
  int t = threadIdx.x;
  bool small_all = true, f32seen = false;
  #pragma unroll
  for (int e = 0; e < 4; ++e) {
    unsigned w = m[t * 4 + e];
    if (w > 1u) small_all = false;
    if (w == 0x3f800000u) f32seen = true;
  }
  unsigned long long ba = __ballot(small_all);
  unsigned long long bf = __ballot(f32seen);
  if (t == 0) *flag = bf ? 1u : (ba == ~0ull ? 1u : 0u);
}

// pack mask into bits: bits[w] bit j = (mask[w*32+j] != 0)
__global__ __launch_bounds__(256) void k_maskpack(const void* __restrict__ maskp,
                                                  const unsigned* __restrict__ flagp,
                                                  unsigned* __restrict__ bits) {
  unsigned wid = blockIdx.x * 256 + threadIdx.x;
  size_t base = (size_t)wid * 32;
  unsigned word = 0;
  if (*flagp == 0) {
    const u32x4* p = (const u32x4*)((const uint8_t*)maskp + base);
    u32x4 v0 = p[0], v1 = p[1];
    #pragma unroll
    for (int e = 0; e < 4; ++e) {
      unsigned d = v0[e];
      #pragma unroll
      for (int by = 0; by < 4; ++by)
        word |= (((d >> (8 * by)) & 0xffu) ? 1u : 0u) << (4 * e + by);
      d = v1[e];
      #pragma unroll
      for (int by = 0; by < 4; ++by)
        word |= (((d >> (8 * by)) & 0xffu) ? 1u : 0u) << (16 + 4 * e + by);
    }
  } else {
    const unsigned* p = (const unsigned*)maskp + base;
    #pragma unroll
    for (int e = 0; e < 32; ++e) word |= (p[e] ? 1u : 0u) << e;
  }
  bits[wid] = word;
}

// ---------------- GEMM kernels (m97-style 128x128, BK=32) ----------------

#define BM 128
#define BN 128
#define BK 32

// C = A[4096x1024] * Wt_z^T ; z=0 -> Q (scaled 1/8*log2e), z=1 -> K, z=2 -> V transposed [B*H*64][SEQ]
__global__ __launch_bounds__(256) void k_gemm_qkv(const unsigned short* __restrict__ A,
                                                  const unsigned short* __restrict__ Wt,
                                                  unsigned short* __restrict__ Qb,
                                                  unsigned short* __restrict__ Kb,
                                                  unsigned short* __restrict__ Vt) {
  __shared__ unsigned short As[BM * BK];
  __shared__ unsigned short Bs[BN * BK];
  int z = blockIdx.y;
  const unsigned short* Bt = Wt + (size_t)z * DM * DM;
  int tid = threadIdx.x;
  int lane = tid & 63, w = tid >> 6;
  int li = lane & 15, g = lane >> 4;
  int bm = blockIdx.x >> 3, bn = blockIdx.x & 7;
  int row0 = bm * BM, col0 = bn * BN;
  int m0 = (w >> 1) * 64, n0 = (w & 1) * 64;
  f32x4 acc[4][4];
  #pragma unroll
  for (int i = 0; i < 4; ++i)
    #pragma unroll
    for (int j = 0; j < 4; ++j) acc[i][j] = (f32x4){0.f, 0.f, 0.f, 0.f};

  const unsigned short* Ag = A + (size_t)(row0 + (tid >> 2)) * DM + (tid & 3) * 8;
  const unsigned short* Bg = Bt + (size_t)(col0 + (tid >> 2)) * DM + (tid & 3) * 8;
  unsigned short* Asl = As + tid * 8;
  unsigned short* Bsl = Bs + tid * 8;

  for (int kk = 0; kk < DM; kk += BK) {
    gload16(Ag + kk, Asl);
    gload16(Ag + kk + (size_t)64 * DM, Asl + 2048);
    gload16(Bg + kk, Bsl);
    gload16(Bg + kk + (size_t)64 * DM, Bsl + 2048);
    __syncthreads();
    bf16x8 af[4], bfr[4];
    #pragma unroll
    for (int mi = 0; mi < 4; ++mi)
      af[mi] = *(const bf16x8*)(As + (m0 + mi * 16 + li) * BK + g * 8);
    #pragma unroll
    for (int ni = 0; ni < 4; ++ni)
      bfr[ni] = *(const bf16x8*)(Bs + (n0 + ni * 16 + li) * BK + g * 8);
    #pragma unroll
    for (int mi = 0; mi < 4; ++mi)
      #pragma unroll
      for (int ni = 0; ni < 4; ++ni)
        acc[mi][ni] = __builtin_amdgcn_mfma_f32_16x16x32_bf16(af[mi], bfr[ni], acc[mi][ni], 0, 0, 0);
    __syncthreads();
  }

  if (z == 2) {
    #pragma unroll
    for (int mi = 0; mi < 4; ++mi)
      #pragma unroll
      for (int ni = 0; ni < 4; ++ni) {
        int mb = row0 + m0 + mi * 16 + g * 4;
        int n = col0 + n0 + ni * 16 + li;
        int bb = mb >> 11, s = mb & 2047;
        u16x4 ov;
        #pragma unroll
        for (int r = 0; r < 4; ++r) ov[r] = f2b(acc[mi][ni][r]);
        *(u16x4*)&Vt[((size_t)(bb * DM + n)) * SEQ + s] = ov;
      }
  } else {
    unsigned short* O = (z == 0) ? Qb : Kb;
    float sc = (z == 0) ? 0.18033688f : 1.0f;  // 0.125 * log2(e): softmax in exp2 domain
    #pragma unroll
    for (int mi = 0; mi < 4; ++mi)
      #pragma unroll
      for (int ni = 0; ni < 4; ++ni) {
        int n = col0 + n0 + ni * 16 + li;
        #pragma unroll
        for (int r = 0; r < 4; ++r) {
          int m = row0 + m0 + mi * 16 + g * 4 + r;
          O[(size_t)m * DM + n] = f2b(acc[mi][ni][r] * sc);
        }
      }
  }
}

__global__ __launch_bounds__(256) void k_gemm_o(const unsigned short* __restrict__ A,
                                                const unsigned short* __restrict__ Bt,
                                                const float* __restrict__ bo,
                                                float* __restrict__ out) {
  __shared__ unsigned short As[BM * BK];
  __shared__ unsigned short Bs[BN * BK];
  int tid = threadIdx.x;
  int lane = tid & 63, w = tid >> 6;
  int li = lane & 15, g = lane >> 4;
  int bm = blockIdx.x >> 3, bn = blockIdx.x & 7;
  int row0 = bm * BM, col0 = bn * BN;
  int m0 = (w >> 1) * 64, n0 = (w & 1) * 64;
  f32x4 acc[4][4];
  #pragma unroll
  for (int i = 0; i < 4; ++i)
    #pragma unroll
    for (int j = 0; j < 4; ++j) acc[i][j] = (f32x4){0.f, 0.f, 0.f, 0.f};

  const unsigned short* Ag = A + (size_t)(row0 + (tid >> 2)) * DM + (tid & 3) * 8;
  const unsigned short* Bg = Bt + (size_t)(col0 + (tid >> 2)) * DM + (tid & 3) * 8;
  unsigned short* Asl = As + tid * 8;
  unsigned short* Bsl = Bs + tid * 8;

  for (int kk = 0; kk < DM; kk += BK) {
    gload16(Ag + kk, Asl);
    gload16(Ag + kk + (size_t)64 * DM, Asl + 2048);
    gload16(Bg + kk, Bsl);
    gload16(Bg + kk + (size_t)64 * DM, Bsl + 2048);
    __syncthreads();
    bf16x8 af[4], bfr[4];
    #pragma unroll
    for (int mi = 0; mi < 4; ++mi)
      af[mi] = *(const bf16x8*)(As + (m0 + mi * 16 + li) * BK + g * 8);
    #pragma unroll
    for (int ni = 0; ni < 4; ++ni)
      bfr[ni] = *(const bf16x8*)(Bs + (n0 + ni * 16 + li) * BK + g * 8);
    #pragma unroll
    for (int mi = 0; mi < 4; ++mi)
      #pragma unroll
      for (int ni = 0; ni < 4; ++ni)
        acc[mi][ni] = __builtin_amdgcn_mfma_f32_16x16x32_bf16(af[mi], bfr[ni], acc[mi][ni], 0, 0, 0);
    __syncthreads();
  }

  #pragma unroll
  for (int mi = 0; mi < 4; ++mi)
    #pragma unroll
    for (int ni = 0; ni < 4; ++ni) {
      int n = col0 + n0 + ni * 16 + li;
      float bias = bo[n];
      #pragma unroll
      for (int r = 0; r < 4; ++r) {
        int m = row0 + m0 + mi * 16 + g * 4 + r;
        out[(size_t)m * DM + n] = acc[mi][ni][r] + bias;
      }
    }
}

// ---------------- flash attention, 1 wave per 32 q-rows, KVBLK=64 ----------------
// Q pre-scaled by 0.125*log2e (exp2 domain). Swapped QK: St = K·Qᵀ (col=query, row=key).
// PV: outᵀ = Vᵀ·Pᵀ via mfma_16x16x16; St C-frag IS the Pᵀ B-frag (zero shuffles).
// Mask via packed bits; defer-max rescale (THR=11.5 in log2 units); XCD-swizzled blocks.
__global__ __launch_bounds__(64, 2) void k_attn(const unsigned short* __restrict__ Qm,
                                                const unsigned short* __restrict__ Km,
                                                const unsigned short* __restrict__ Vt,
                                                const unsigned* __restrict__ bits,
                                                unsigned short* __restrict__ AO) {
  const int lane = threadIdx.x;
  const int li = lane & 15, g = lane >> 4;
  // XCD swizzle: 2048 blocks -> each XCD gets 256 contiguous work-ids (4 (b,h) groups, ~2.5MB hot set)
  unsigned id = blockIdx.x;
  unsigned swz = (id & 7) * 256 + (id >> 3);
  const int q0 = (swz & 63) * 32;
  const int h = (swz >> 6) & 15;
  const int b = swz >> 10;
  const size_t qrow0 = (size_t)b * SEQ + q0;

  bf16x8 qf[2][2];
  #pragma unroll
  for (int is = 0; is < 2; ++is)
    #pragma unroll
    for (int kc = 0; kc < 2; ++kc)
      qf[is][kc] = *(const bf16x8*)(Qm + (qrow0 + is * 16 + li) * DM + h * HD + kc * 32 + g * 8);

  f32x4 acc[2][4];
  #pragma unroll
  for (int is = 0; is < 2; ++is)
    #pragma unroll
    for (int ds = 0; ds < 4; ++ds) acc[is][ds] = (f32x4){0.f, 0.f, 0.f, 0.f};
  float m[2] = {-1e30f, -1e30f};
  float l[2] = {0.f, 0.f};

  const unsigned short* Kbase = Km + (size_t)b * SEQ * DM + h * HD + g * 8;
  const unsigned short* Vbase = Vt + (size_t)(b * NHEAD + h) * HD * SEQ + g * 4;
  const unsigned* mr[2] = {bits + (qrow0 + li) * (SEQ / 32),
                           bits + (qrow0 + 16 + li) * (SEQ / 32)};

  for (int j0 = 0; j0 < SEQ; j0 += 64) {
    // K fragments for 4 key-tiles
    bf16x8 kf[4][2];
    #pragma unroll
    for (int kt = 0; kt < 4; ++kt) {
      kf[kt][0] = *(const bf16x8*)(Kbase + (size_t)(j0 + kt * 16 + li) * DM);
      kf[kt][1] = *(const bf16x8*)(Kbase + (size_t)(j0 + kt * 16 + li) * DM + 32);
    }
    unsigned mw[2][2];
    #pragma unroll
    for (int is = 0; is < 2; ++is) {
      mw[is][0] = mr[is][(j0 >> 5)];
      mw[is][1] = mr[is][(j0 >> 5) + 1];
    }
    // QK^T for both q-subtiles
    f32x4 st[2][4];
    #pragma unroll
    for (int is = 0; is < 2; ++is)
      #pragma unroll
      for (int kt = 0; kt < 4; ++kt) {
        f32x4 zz = (f32x4){0.f, 0.f, 0.f, 0.f};
        st[is][kt] = __builtin_amdgcn_mfma_f32_16x16x32_bf16(kf[kt][0], qf[is][0], zz, 0, 0, 0);
        st[is][kt] = __builtin_amdgcn_mfma_f32_16x16x32_bf16(kf[kt][1], qf[is][1], st[is][kt], 0, 0, 0);
      }
    // V fragments (issued here; consumed after softmax -> latency hidden)
    s16x4 vf[4][4];
    #pragma unroll
    for (int ds = 0; ds < 4; ++ds)
      #pragma unroll
      for (int kt = 0; kt < 4; ++kt)
        vf[ds][kt] = *(const s16x4*)(Vbase + (size_t)(ds * 16 + li) * SEQ + j0 + kt * 16);

    // mask + row max
    float tm[2] = {-1e30f, -1e30f};
    #pragma unroll
    for (int is = 0; is < 2; ++is) {
      #pragma unroll
      for (int kt = 0; kt < 4; ++kt) {
        #pragma unroll
        for (int r = 0; r < 4; ++r) {
          int c = kt * 16 + g * 4 + r;
          unsigned bit = (mw[is][kt >> 1] >> (c & 31)) & 1u;
          st[is][kt][r] = bit ? st[is][kt][r] : -1e30f;
          tm[is] = fmaxf(tm[is], st[is][kt][r]);
        }
      }
      tm[is] = fmaxf(tm[is], __shfl_xor(tm[is], 16));
      tm[is] = fmaxf(tm[is], __shfl_xor(tm[is], 32));
    }
    // defer-max: rescale only when max grows by > 11.5 (= e^8 in exp2 domain)
    bool need = (tm[0] > m[0] + 11.5f) || (tm[1] > m[1] + 11.5f);
    if (__any(need)) {
      #pragma unroll
      for (int is = 0; is < 2; ++is) {
        float mn = fmaxf(m[is], tm[is]);
        float a = exp2f(m[is] - mn);
        m[is] = mn;
        l[is] *= a;
        #pragma unroll
        for (int ds = 0; ds < 4; ++ds) acc[is][ds] *= a;
      }
    }
    // P = 2^(S - m), masked; sum; PV
    #pragma unroll
    for (int is = 0; is < 2; ++is) {
      float ps = 0.f;
      bf16x4 pb[4];
      #pragma unroll
      for (int kt = 0; kt < 4; ++kt) {
        #pragma unroll
        for (int r = 0; r < 4; ++r) {
          float ex = exp2f(st[is][kt][r] - m[is]);
          ex = (st[is][kt][r] < -1e29f) ? 0.f : ex;  // exact 0 for masked (covers stale-m edge)
          ps += ex;
          pb[kt][r] = (__bf16)ex;
        }
      }
      ps += __shfl_xor(ps, 16);
      ps += __shfl_xor(ps, 32);
      l[is] += ps;
      #pragma unroll
      for (int ds = 0; ds < 4; ++ds) {
        #pragma unroll
        for (int kt = 0; kt < 4; ++kt)
          acc[is][ds] = __builtin_amdgcn_mfma_f32_16x16x16bf16_1k(
              vf[ds][kt], __builtin_bit_cast(s16x4, pb[kt]), acc[is][ds], 0, 0, 0);
      }
    }
  }

  #pragma unroll
  for (int is = 0; is < 2; ++is) {
    float inv = 1.f / fmaxf(l[is], 1e-9f);
    #pragma unroll
    for (int ds = 0; ds < 4; ++ds) {
      u16x4 ov;
      #pragma unroll
      for (int r = 0; r < 4; ++r) ov[r] = f2b(acc[is][ds][r] * inv);
      *(u16x4*)(AO + (qrow0 + is * 16 + li) * DM + h * HD + ds * 16 + g * 4) = ov;
    }
  }
}

// ---------------- launch ----------------

extern "C" void kernel_launch(void* const* d_in, const int* in_sizes, int n_in,
                              void* d_out, int out_size, void* d_ws, size_t ws_size,
                              hipStream_t stream) {
  const float* x = (const float*)d_in[0];
  const void* mk = d_in[1];
  const float* Wq = (const float*)d_in[2];
  const float* Wk = (const float*)d_in[3];
  const float* Wv = (const float*)d_in[4];
  const float* Wo = (const float*)d_in[5];
  const float* bo = (const float*)d_in[6];
  float* out = (float*)d_out;
  char* ws = (char*)d_ws;

  // workspace layout (41 MB + 4 B):
  //   [0,8)   MB : xb (bf16 x) -- dead after k_gemm_qkv; reused as AO
  //   [8,16)  MB : wt (4x Wt^T bf16)
  //   [16,24) MB : Qb
  //   [24,32) MB : Kb
  //   [32,40) MB : Vt
  //   [40,41) MB : mask bits
  //   41 MB      : flag
  unsigned short* xb = (unsigned short*)(ws);
  unsigned short* wt = (unsigned short*)(ws + ((size_t)8 << 20));
  unsigned short* Qb = (unsigned short*)(ws + ((size_t)16 << 20));
  unsigned short* Kb = (unsigned short*)(ws + ((size_t)24 << 20));
  unsigned short* Vt = (unsigned short*)(ws + ((size_t)32 << 20));
  unsigned* bits = (unsigned*)(ws + ((size_t)40 << 20));
  unsigned short* AO = xb;  // alias: xb dead after k_gemm_qkv
  unsigned* flag = (unsigned*)(ws + ((size_t)41 << 20));

  hipLaunchKernelGGL(k_conv_x, dim3(2048), dim3(256), 0, stream, x, xb);
  hipLaunchKernelGGL(k_conv_wt, dim3(32, 32, 4), dim3(256), 0, stream, Wq, Wk, Wv, Wo, wt);
  hipLaunchKernelGGL(k_probe, dim3(1), dim3(64), 0, stream, (const unsigned*)mk, flag);
  hipLaunchKernelGGL(k_maskpack, dim3(1024), dim3(256), 0, stream, mk, flag, bits);
  hipLaunchKernelGGL(k_gemm_qkv, dim3(256, 3), dim3(256), 0, stream, xb, wt, Qb, Kb, Vt);
  hipLaunchKernelGGL(k_attn, dim3(2048), dim3(64), 0, stream, Qb, Kb, Vt, bits, AO);
  hipLaunchKernelGGL(k_gemm_o, dim3(256), dim3(256), 0, stream, AO, wt + (size_t)3 * DM * DM, bo, out);
}